// Round 5
// baseline (639.705 us; speedup 1.0000x reference)
//
#include <hip/hip_runtime.h>
#include <hip/hip_bf16.h>

// EdgeGNN layer: linear1(relu) -> SpMM (CSR counting-sort + gather) -> linear2(relu) -> GRUCell
// E=200000, NNZ=1600000, EF=16, M=128. bf16 MFMA for GEMMs; no f32 atomics.
// R4: (a) gru epilogue accumulates in registers, single coalesced store burst at
//     end (kills the 4.5x WRITE_SIZE amplification seen in R3: 463MB vs 102MB ideal);
//     (b) gate-weight LDS tiles double-buffered (48KB) -> 1 barrier/phase not 2;
//     (c) gather_kernel software-pipelined 2 deep (csr +2, gathered row +1).

typedef __attribute__((ext_vector_type(4))) float f32x4;
typedef __attribute__((ext_vector_type(8))) short s16x8;

#define MDIM 128
#define EFDIM 16
#define K1PAD 160   // 144 padded to 5*32
#define SCAN_BLK 1024

__device__ __forceinline__ ushort f2bf(float f) {
  union { float f; unsigned u; } v; v.f = f;
  unsigned u = v.u;
  unsigned r = (u + 0x7fffu + ((u >> 16) & 1u)) >> 16;  // RNE
  return (ushort)r;
}
__device__ __forceinline__ float bf2f(ushort h) {
  union { unsigned u; float f; } v; v.u = ((unsigned)h) << 16; return v.f;
}
__device__ __forceinline__ s16x8 cvt8(f32x4 a, f32x4 b) {
  s16x8 o;
  o[0] = (short)f2bf(a[0]); o[1] = (short)f2bf(a[1]);
  o[2] = (short)f2bf(a[2]); o[3] = (short)f2bf(a[3]);
  o[4] = (short)f2bf(b[0]); o[5] = (short)f2bf(b[1]);
  o[6] = (short)f2bf(b[2]); o[7] = (short)f2bf(b[3]);
  return o;
}
__device__ __forceinline__ f32x4 mfma16(s16x8 a, s16x8 b, f32x4 c) {
  return __builtin_amdgcn_mfma_f32_16x16x32_bf16(a, b, c, 0, 0, 0);
}
__device__ __forceinline__ float sigmoidf_(float x) { return 1.f / (1.f + __expf(-x)); }
__device__ __forceinline__ float tanhf_(float x) {
  float xc = fminf(fmaxf(x, -15.f), 15.f);
  float t = __expf(2.f * xc);
  return (t - 1.f) / (t + 1.f);
}

// ---------------- prep: bf16 weight conversion ----------------
__global__ __launch_bounds__(256) void prep_kernel(
    const float* __restrict__ W1, const float* __restrict__ W2,
    const float* __restrict__ Wih, const float* __restrict__ Whh,
    ushort* __restrict__ W1b, ushort* __restrict__ W2b,
    ushort* __restrict__ Wihb, ushort* __restrict__ Whhb) {
  int idx = blockIdx.x * 256 + threadIdx.x;
  if (idx < 128 * K1PAD) {
    int n = idx / K1PAD, k = idx % K1PAD;
    W1b[idx] = (k < 144) ? f2bf(W1[n * 144 + k]) : (ushort)0;
    return;
  }
  int i2 = idx - 128 * K1PAD;
  if (i2 < 128 * 128) { W2b[i2] = f2bf(W2[i2]); return; }
  int i3 = i2 - 128 * 128;
  if (i3 < 384 * 128) { Wihb[i3] = f2bf(Wih[i3]); return; }
  int i4 = i3 - 384 * 128;
  if (i4 < 384 * 128) { Whhb[i4] = f2bf(Whh[i4]); return; }
}

// ---------------- K1: msg1 = relu(concat(mo,ef) @ W1^T + b1), bf16 out ----------------
__global__ __launch_bounds__(256) void linear1_kernel(
    const float* __restrict__ mo, const float* __restrict__ ef,
    const ushort* __restrict__ W1b, const float* __restrict__ b1,
    ushort* __restrict__ msg1b) {
  __shared__ ushort w1l[128 * 192];  // 48KB
  const int tid = threadIdx.x;
  const int wave = tid >> 6, lane = tid & 63;
  const int r = lane & 15, kg = lane >> 4;
  const int row0 = blockIdx.x * 64 + wave * 16;
  const int arow = row0 + r;

#pragma unroll
  for (int l = 0; l < 10; ++l) {
    const int gid = l * 256 + tid;
    const int row = gid / 20, g = gid - row * 20;
    uint4 v = *(const uint4*)(W1b + row * K1PAD + g * 8);
    *(uint4*)&w1l[row * 192 + ((g ^ (row & 7)) * 8)] = v;
  }
  __syncthreads();

  f32x4 acc[8] = {};
#pragma unroll
  for (int step = 0; step < 5; ++step) {
    const int k0 = step * 32 + kg * 8;
    s16x8 a;
    if (k0 < 128) {
      f32x4 f1 = *(const f32x4*)(mo + (size_t)arow * MDIM + k0);
      f32x4 f2 = *(const f32x4*)(mo + (size_t)arow * MDIM + k0 + 4);
      a = cvt8(f1, f2);
    } else if (k0 < 144) {
      f32x4 f1 = *(const f32x4*)(ef + (size_t)arow * EFDIM + (k0 - 128));
      f32x4 f2 = *(const f32x4*)(ef + (size_t)arow * EFDIM + (k0 - 128) + 4);
      a = cvt8(f1, f2);
    } else {
      a = (s16x8){0, 0, 0, 0, 0, 0, 0, 0};
    }
#pragma unroll
    for (int f = 0; f < 8; ++f) {
      const int col = f * 16 + r;
      s16x8 b = *(const s16x8*)&w1l[col * 192 + (((step * 4 + kg) ^ (col & 7)) * 8)];
      acc[f] = mfma16(a, b, acc[f]);
    }
  }
#pragma unroll
  for (int f = 0; f < 8; ++f) {
    const int col = f * 16 + r;
    const float bias = b1[col];
#pragma unroll
    for (int j = 0; j < 4; ++j) {
      const int orow = row0 + kg * 4 + j;
      float v = acc[f][j] + bias;
      v = v > 0.f ? v : 0.f;
      msg1b[(size_t)orow * MDIM + col] = f2bf(v);
    }
  }
}

// ---------------- CSR build: histogram -> scan -> scatter ----------------
__global__ __launch_bounds__(256) void hist_kernel(const int* __restrict__ rows,
                                                   int* __restrict__ cnt, int nnz) {
  int i = blockIdx.x * 256 + threadIdx.x;
  if (i < nnz) atomicAdd(&cnt[rows[i]], 1);
}

__global__ __launch_bounds__(256) void scan1_kernel(const int* __restrict__ cnt,
                                                    int* __restrict__ excl,
                                                    int* __restrict__ bsums, int n) {
  __shared__ int wsum[4];
  const int t = threadIdx.x;
  const int base = blockIdx.x * SCAN_BLK + t * 4;
  int v[4];
#pragma unroll
  for (int j = 0; j < 4; ++j) v[j] = (base + j < n) ? cnt[base + j] : 0;
  const int s = v[0] + v[1] + v[2] + v[3];
  const int lane = t & 63, wave = t >> 6;
  int inc = s;
#pragma unroll
  for (int d = 1; d < 64; d <<= 1) {
    int o = __shfl_up(inc, d, 64);
    if (lane >= d) inc += o;
  }
  if (lane == 63) wsum[wave] = inc;
  __syncthreads();
  int woff = 0;
#pragma unroll
  for (int wv = 0; wv < 4; ++wv) if (wv < wave) woff += wsum[wv];
  int run = woff + inc - s;
#pragma unroll
  for (int j = 0; j < 4; ++j) {
    if (base + j < n) excl[base + j] = run;
    run += v[j];
  }
  if (t == 0) bsums[blockIdx.x] = wsum[0] + wsum[1] + wsum[2] + wsum[3];
}

__global__ __launch_bounds__(256) void scan2_kernel(int* __restrict__ bsums, int nb) {
  __shared__ int ws[4];
  const int t = threadIdx.x;
  const int v = (t < nb) ? bsums[t] : 0;
  const int lane = t & 63, wave = t >> 6;
  int inc = v;
#pragma unroll
  for (int d = 1; d < 64; d <<= 1) {
    int o = __shfl_up(inc, d, 64);
    if (lane >= d) inc += o;
  }
  if (lane == 63) ws[wave] = inc;
  __syncthreads();
  int woff = 0;
#pragma unroll
  for (int wv = 0; wv < 4; ++wv) if (wv < wave) woff += ws[wv];
  if (t < nb) bsums[t] = woff + inc - v;
}

__global__ __launch_bounds__(256) void scan3_kernel(int* __restrict__ row_ptr,
                                                    int* __restrict__ row_fill,
                                                    const int* __restrict__ bsums, int n) {
  int i = blockIdx.x * 256 + threadIdx.x;
  if (i >= n) return;
  int v = row_ptr[i] + bsums[i / SCAN_BLK];
  row_ptr[i] = v;
  row_fill[i] = v;
}

__global__ __launch_bounds__(256) void scatter_kernel(
    const int* __restrict__ rows, const int* __restrict__ cols,
    const float* __restrict__ vals, int* __restrict__ row_fill,
    int2* __restrict__ csr, int nnz) {
  int i = blockIdx.x * 256 + threadIdx.x;
  if (i >= nnz) return;
  int r = rows[i];
  int idx = atomicAdd(&row_fill[r], 1);
  int2 cv;
  cv.x = cols[i];
  cv.y = __float_as_int(vals[i]);
  csr[idx] = cv;
}

// ---------------- gather SpMM: one wave per row, 2-stage pipeline ----------------
__global__ __launch_bounds__(256) void gather_kernel(
    const int* __restrict__ row_ptr, const int2* __restrict__ csr,
    const ushort* __restrict__ msg1b, ushort* __restrict__ msg2b,
    int E, int nnz) {
  const int w = (blockIdx.x * 256 + threadIdx.x) >> 6;
  if (w >= E) return;
  const int lane = threadIdx.x & 63;
  const int start = row_ptr[w];
  const int end = (w == E - 1) ? nnz : row_ptr[w + 1];
  float a0 = 0.f, a1 = 0.f;

  int2 cvA = {0, 0}, cvB = {0, 0};
  ushort2 mA = {0, 0};
  if (start < end) {
    cvA = csr[start];
    mA = *(const ushort2*)(msg1b + (size_t)cvA.x * MDIM + lane * 2);
  }
  if (start + 1 < end) cvB = csr[start + 1];

  for (int j = start; j < end; ++j) {
    int2 cvC = cvB;
    ushort2 mB = mA;
    if (j + 2 < end) cvC = csr[j + 2];
    if (j + 1 < end) mB = *(const ushort2*)(msg1b + (size_t)cvB.x * MDIM + lane * 2);
    const float val = __int_as_float(cvA.y);
    a0 += bf2f(mA.x) * val;
    a1 += bf2f(mA.y) * val;
    cvA = cvB; cvB = cvC; mA = mB;
  }
  ushort2 o;
  o.x = f2bf(a0);
  o.y = f2bf(a1);
  *(ushort2*)(msg2b + (size_t)w * MDIM + lane * 2) = o;
}

// ---------------- K4: fused linear2(relu) + GRUCell ----------------
// 48KB LDS. Phase 0: mo -> buf[0,8192). Phase 1: stage1 GEMM, W2 ping-pong at
// [8192,12288). Phase 2: gate GEMMs, 6-section 12KB weight tile sets ping-ponged
// between [0,12288) and [12288,24576) -> ONE barrier per phase. Outputs held in
// registers; single coalesced store burst at the end (full-line L2 evictions).
__global__ __launch_bounds__(256) void gru_kernel(
    const ushort* __restrict__ msg2b, const float* __restrict__ mo,
    const ushort* __restrict__ W2b, const float* __restrict__ b2,
    const ushort* __restrict__ Wihb, const ushort* __restrict__ Whhb,
    const float* __restrict__ bih, const float* __restrict__ bhh,
    float* __restrict__ out) {
  __shared__ ushort lds[24576];  // 48KB
  const int tid = threadIdx.x;
  const int wave = tid >> 6, lane = tid & 63;
  const int r = lane & 15, kg = lane >> 4;
  const int row0 = blockIdx.x * 64;
  const int wrow = row0 + wave * 16;
  const int rid = tid >> 4, gg = tid & 15;  // staging coords

  // ---- phase 0: mo -> buf (bf16, swizzled) ----
#pragma unroll
  for (int it = 0; it < 8; ++it) {
    const int idx = it * 256 + tid;
    const int rr = idx >> 5, c4 = (idx & 31) * 4;
    f32x4 v = *(const f32x4*)(mo + (size_t)(row0 + rr) * MDIM + c4);
    ushort4 u;
    u.x = f2bf(v[0]); u.y = f2bf(v[1]); u.z = f2bf(v[2]); u.w = f2bf(v[3]);
    *(ushort4*)&lds[rr * 128 + (c4 ^ ((rr & 7) << 3))] = u;
  }
  __syncthreads();

  // hoist ah (A-fragments of message_old) + packed mo epilogue values (own-wave rows)
  s16x8 ah[4];
#pragma unroll
  for (int step = 0; step < 4; ++step) {
    const int row = wave * 16 + r, k0 = step * 32 + kg * 8;
    ah[step] = *(const s16x8*)&lds[row * 128 + (k0 ^ ((row & 7) << 3))];
  }
  uint mo_pk[16];
#pragma unroll
  for (int f = 0; f < 8; ++f) {
#pragma unroll
    for (int jj = 0; jj < 2; ++jj) {
      const int rl0 = wave * 16 + kg * 4 + jj * 2;
      const int col = f * 16 + r;
      ushort u0 = lds[rl0 * 128 + (col ^ ((rl0 & 7) << 3))];
      ushort u1 = lds[(rl0 + 1) * 128 + (col ^ (((rl0 + 1) & 7) << 3))];
      mo_pk[f * 2 + jj] = (uint)u0 | ((uint)u1 << 16);
    }
  }

  // ---- phase 1: stage1 GEMM (msg3 = relu(msg2 @ W2^T + b2)) -> buf ----
  s16x8 a1[4];
#pragma unroll
  for (int step = 0; step < 4; ++step)
    a1[step] = *(const s16x8*)(msg2b + (size_t)(wrow + r) * MDIM + step * 32 + kg * 8);

  {
    uint4 w2reg = *(const uint4*)(W2b + (size_t)rid * 128 + gg * 8);  // f=0 tile
    *(uint4*)&lds[8192 + rid * 128 + ((gg * 8) ^ ((rid & 7) << 3))] = w2reg;
#pragma unroll
    for (int f = 0; f < 8; ++f) {
      if (f < 7)
        w2reg = *(const uint4*)(W2b + (size_t)((f + 1) * 16 + rid) * 128 + gg * 8);
      __syncthreads();
      f32x4 acc = {};
#pragma unroll
      for (int step = 0; step < 4; ++step) {
        const int k0 = step * 32 + kg * 8;
        s16x8 b = *(const s16x8*)&lds[8192 + (f & 1) * 2048 + r * 128 + (k0 ^ ((r & 7) << 3))];
        acc = mfma16(a1[step], b, acc);
      }
      const int col = f * 16 + r;
      const float bias = b2[col];
#pragma unroll
      for (int j = 0; j < 4; ++j) {
        const int rl = wave * 16 + kg * 4 + j;
        float v = acc[j] + bias;
        v = v > 0.f ? v : 0.f;
        lds[rl * 128 + (col ^ ((rl & 7) << 3))] = f2bf(v);
      }
      if (f < 7)
        *(uint4*)&lds[8192 + ((f + 1) & 1) * 2048 + rid * 128 + ((gg * 8) ^ ((rid & 7) << 3))] = w2reg;
    }
  }

  // issue f=0 gate-weight loads early, hoist ai (own-wave rows), then barrier
  uint4 wreg[6];
#pragma unroll
  for (int l = 0; l < 6; ++l) {
    const ushort* src = (l & 1) ? Whhb : Wihb;
    const int gate = l >> 1;
    wreg[l] = *(const uint4*)(src + (size_t)(gate * 128 + rid) * 128 + gg * 8);
  }
  s16x8 ai[4];
#pragma unroll
  for (int step = 0; step < 4; ++step) {
    const int row = wave * 16 + r, k0 = step * 32 + kg * 8;
    ai[step] = *(const s16x8*)&lds[row * 128 + (k0 ^ ((row & 7) << 3))];
  }
  __syncthreads();  // all buf/w2 readers done before wt slot0 overwrites

  // ---- phase 2: gate GEMMs, ping-pong 12KB tile sets, 1 barrier/phase ----
  // slot s base = s*12288; section l at base + l*2048.
  // sec: 0=Wih.r 1=Whh.r 2=Wih.z 3=Whh.z 4=Wih.n 5=Whh.n
#pragma unroll
  for (int l = 0; l < 6; ++l)
    *(uint4*)&lds[0 * 12288 + l * 2048 + rid * 128 + ((gg * 8) ^ ((rid & 7) << 3))] = wreg[l];

  float outv[32];
#pragma unroll
  for (int f = 0; f < 8; ++f) {
    if (f < 7) {
#pragma unroll
      for (int l = 0; l < 6; ++l) {
        const ushort* src = (l & 1) ? Whhb : Wihb;
        const int gate = l >> 1;
        wreg[l] = *(const uint4*)(src + (size_t)(gate * 128 + (f + 1) * 16 + rid) * 128 + gg * 8);
      }
    }
    __syncthreads();  // slot f&1 visible; prior readers of slot (f+1)&1 done
    const int wbase = ((f + 1) & 1) * 12288;
    if (f < 7) {
#pragma unroll
      for (int l = 0; l < 6; ++l)
        *(uint4*)&lds[wbase + l * 2048 + rid * 128 + ((gg * 8) ^ ((rid & 7) << 3))] = wreg[l];
    }
    const int rbase = (f & 1) * 12288;
    f32x4 a_ir = {}, a_hr = {}, a_iz = {}, a_hz = {}, a_in = {}, a_hn = {};
#pragma unroll
    for (int step = 0; step < 4; ++step) {
      const int k0 = step * 32 + kg * 8;
      const int sw = (k0 ^ ((r & 7) << 3)) + r * 128;
      s16x8 b_ir = *(const s16x8*)&lds[rbase + 0 * 2048 + sw];
      s16x8 b_hr = *(const s16x8*)&lds[rbase + 1 * 2048 + sw];
      a_ir = mfma16(ai[step], b_ir, a_ir);
      a_hr = mfma16(ah[step], b_hr, a_hr);
      s16x8 b_iz = *(const s16x8*)&lds[rbase + 2 * 2048 + sw];
      s16x8 b_hz = *(const s16x8*)&lds[rbase + 3 * 2048 + sw];
      a_iz = mfma16(ai[step], b_iz, a_iz);
      a_hz = mfma16(ah[step], b_hz, a_hz);
      s16x8 b_in = *(const s16x8*)&lds[rbase + 4 * 2048 + sw];
      s16x8 b_hn = *(const s16x8*)&lds[rbase + 5 * 2048 + sw];
      a_in = mfma16(ai[step], b_in, a_in);
      a_hn = mfma16(ah[step], b_hn, a_hn);
    }
    const int cr = f * 16 + r, cz = 128 + cr, cn = 256 + cr;
    const float bi_r = bih[cr], bh_r = bhh[cr];
    const float bi_z = bih[cz], bh_z = bhh[cz];
    const float bi_n = bih[cn], bh_n = bhh[cn];
#pragma unroll
    for (int j = 0; j < 4; ++j) {
      const float rr_ = sigmoidf_((a_ir[j] + bi_r) + (a_hr[j] + bh_r));
      const float zz = sigmoidf_((a_iz[j] + bi_z) + (a_hz[j] + bh_z));
      const float nn = tanhf_((a_in[j] + bi_n) + rr_ * (a_hn[j] + bh_n));
      const uint pk = mo_pk[f * 2 + (j >> 1)];
      const float m = bf2f((ushort)((j & 1) ? (pk >> 16) : (pk & 0xffffu)));
      outv[f * 4 + j] = (1.f - zz) * nn + zz * m;
    }
  }

  // coalesced store burst: all writes to each 64-row tile issued back-to-back
#pragma unroll
  for (int j = 0; j < 4; ++j) {
    const int rl = wave * 16 + kg * 4 + j;
    float* dst = out + (size_t)(row0 + rl) * MDIM;
#pragma unroll
    for (int f = 0; f < 8; ++f)
      dst[f * 16 + r] = outv[f * 4 + j];
  }
}

extern "C" void kernel_launch(void* const* d_in, const int* in_sizes, int n_in,
                              void* d_out, int out_size, void* d_ws, size_t ws_size,
                              hipStream_t stream) {
  const float* ef   = (const float*)d_in[0];
  const float* mo   = (const float*)d_in[1];
  const int*   arow = (const int*)d_in[2];
  const int*   acol = (const int*)d_in[3];
  const float* aval = (const float*)d_in[4];
  const float* W1   = (const float*)d_in[5];
  const float* b1   = (const float*)d_in[6];
  const float* W2   = (const float*)d_in[7];
  const float* b2   = (const float*)d_in[8];
  const float* Wih  = (const float*)d_in[9];
  const float* Whh  = (const float*)d_in[10];
  const float* bih  = (const float*)d_in[11];
  const float* bhh  = (const float*)d_in[12];
  float* out = (float*)d_out;

  const int E   = in_sizes[0] / EFDIM;   // 200000
  const int nnz = in_sizes[2];           // 1600000

  char* w = (char*)d_ws;
  size_t off = 0;
  ushort* msg1b   = (ushort*)(w + off); off += (size_t)E * MDIM * 2;   // 51.2 MB
  ushort* msg2b   = (ushort*)(w + off); off += (size_t)E * MDIM * 2;   // 51.2 MB
  int*    row_cnt = (int*)(w + off);    off += (size_t)E * 4;
  int*    row_ptr = (int*)(w + off);    off += (size_t)E * 4;
  int*    row_fill= (int*)(w + off);    off += (size_t)E * 4;
  int*    bsums   = (int*)(w + off);    off += 256 * 4;
  int2*   csr     = (int2*)(w + off);   off += (size_t)nnz * 8;        // 12.8 MB
  ushort* W1b     = (ushort*)(w + off); off += 128 * K1PAD * 2;
  ushort* W2b     = (ushort*)(w + off); off += 128 * 128 * 2;
  ushort* Wihb    = (ushort*)(w + off); off += 384 * 128 * 2;
  ushort* Whhb    = (ushort*)(w + off); off += 384 * 128 * 2;
  if (off > ws_size) return;  // needs ~118 MB

  const int prep_elems = 128 * K1PAD + 128 * 128 + 2 * 384 * 128;
  prep_kernel<<<(prep_elems + 255) / 256, 256, 0, stream>>>(W1, W2, Wih, Whh,
                                                            W1b, W2b, Wihb, Whhb);
  // linear1
  linear1_kernel<<<E / 64, 256, 0, stream>>>(mo, ef, W1b, b1, msg1b);

  // CSR build
  hipMemsetAsync(row_cnt, 0, (size_t)E * 4, stream);
  hist_kernel<<<(nnz + 255) / 256, 256, 0, stream>>>(arow, row_cnt, nnz);
  const int nscan = (E + SCAN_BLK - 1) / SCAN_BLK;  // 196 blocks
  scan1_kernel<<<nscan, 256, 0, stream>>>(row_cnt, row_ptr, bsums, E);
  scan2_kernel<<<1, 256, 0, stream>>>(bsums, nscan);
  scan3_kernel<<<(E + 255) / 256, 256, 0, stream>>>(row_ptr, row_fill, bsums, E);
  scatter_kernel<<<(nnz + 255) / 256, 256, 0, stream>>>(arow, acol, aval, row_fill, csr, nnz);

  // gather SpMM
  {
    const long long total = (long long)E * 64;
    const int grid = (int)((total + 255) / 256);
    gather_kernel<<<grid, 256, 0, stream>>>(row_ptr, csr, msg1b, msg2b, E, nnz);
  }

  // fused linear2 + GRU
  gru_kernel<<<E / 64, 256, 0, stream>>>(msg2b, mo, W2b, b2, Wihb, Whhb, bih, bhh, out);
}

// Round 6
// 502.514 us; speedup vs baseline: 1.2730x; 1.2730x over previous
//
#include <hip/hip_runtime.h>
#include <hip/hip_bf16.h>

// EdgeGNN layer: linear1(relu) -> SpMM (CSR counting-sort + gather) -> linear2(relu) -> GRUCell
// E=200000, NNZ=1600000, EF=16, M=128. bf16 MFMA for GEMMs; no f32 atomics.
// R5: gru split into msg3_kernel (plain GEMM) + gate_kernel (4-way column-split,
//     weights staged ONCE per block, zero main-loop barriers). R4's 8-barrier
//     ping-pong structure was occupancy/latency-bound (11% occ, VGPR 176).

typedef __attribute__((ext_vector_type(4))) float f32x4;
typedef __attribute__((ext_vector_type(8))) short s16x8;

#define MDIM 128
#define EFDIM 16
#define K1PAD 160   // 144 padded to 5*32
#define SCAN_BLK 1024

__device__ __forceinline__ ushort f2bf(float f) {
  union { float f; unsigned u; } v; v.f = f;
  unsigned u = v.u;
  unsigned r = (u + 0x7fffu + ((u >> 16) & 1u)) >> 16;  // RNE
  return (ushort)r;
}
__device__ __forceinline__ float bf2f(ushort h) {
  union { unsigned u; float f; } v; v.u = ((unsigned)h) << 16; return v.f;
}
__device__ __forceinline__ s16x8 cvt8(f32x4 a, f32x4 b) {
  s16x8 o;
  o[0] = (short)f2bf(a[0]); o[1] = (short)f2bf(a[1]);
  o[2] = (short)f2bf(a[2]); o[3] = (short)f2bf(a[3]);
  o[4] = (short)f2bf(b[0]); o[5] = (short)f2bf(b[1]);
  o[6] = (short)f2bf(b[2]); o[7] = (short)f2bf(b[3]);
  return o;
}
__device__ __forceinline__ f32x4 mfma16(s16x8 a, s16x8 b, f32x4 c) {
  return __builtin_amdgcn_mfma_f32_16x16x32_bf16(a, b, c, 0, 0, 0);
}
__device__ __forceinline__ float sigmoidf_(float x) { return 1.f / (1.f + __expf(-x)); }
__device__ __forceinline__ float tanhf_(float x) {
  float xc = fminf(fmaxf(x, -15.f), 15.f);
  float t = __expf(2.f * xc);
  return (t - 1.f) / (t + 1.f);
}

// ---------------- prep: bf16 weight conversion ----------------
__global__ __launch_bounds__(256) void prep_kernel(
    const float* __restrict__ W1, const float* __restrict__ W2,
    const float* __restrict__ Wih, const float* __restrict__ Whh,
    ushort* __restrict__ W1b, ushort* __restrict__ W2b,
    ushort* __restrict__ Wihb, ushort* __restrict__ Whhb) {
  int idx = blockIdx.x * 256 + threadIdx.x;
  if (idx < 128 * K1PAD) {
    int n = idx / K1PAD, k = idx % K1PAD;
    W1b[idx] = (k < 144) ? f2bf(W1[n * 144 + k]) : (ushort)0;
    return;
  }
  int i2 = idx - 128 * K1PAD;
  if (i2 < 128 * 128) { W2b[i2] = f2bf(W2[i2]); return; }
  int i3 = i2 - 128 * 128;
  if (i3 < 384 * 128) { Wihb[i3] = f2bf(Wih[i3]); return; }
  int i4 = i3 - 384 * 128;
  if (i4 < 384 * 128) { Whhb[i4] = f2bf(Whh[i4]); return; }
}

// ---------------- K1: msg1 = relu(concat(mo,ef) @ W1^T + b1), bf16 out ----------------
__global__ __launch_bounds__(256) void linear1_kernel(
    const float* __restrict__ mo, const float* __restrict__ ef,
    const ushort* __restrict__ W1b, const float* __restrict__ b1,
    ushort* __restrict__ msg1b) {
  __shared__ ushort w1l[128 * 192];  // 48KB
  const int tid = threadIdx.x;
  const int wave = tid >> 6, lane = tid & 63;
  const int r = lane & 15, kg = lane >> 4;
  const int row0 = blockIdx.x * 64 + wave * 16;
  const int arow = row0 + r;

#pragma unroll
  for (int l = 0; l < 10; ++l) {
    const int gid = l * 256 + tid;
    const int row = gid / 20, g = gid - row * 20;
    uint4 v = *(const uint4*)(W1b + row * K1PAD + g * 8);
    *(uint4*)&w1l[row * 192 + ((g ^ (row & 7)) * 8)] = v;
  }
  __syncthreads();

  f32x4 acc[8] = {};
#pragma unroll
  for (int step = 0; step < 5; ++step) {
    const int k0 = step * 32 + kg * 8;
    s16x8 a;
    if (k0 < 128) {
      f32x4 f1 = *(const f32x4*)(mo + (size_t)arow * MDIM + k0);
      f32x4 f2 = *(const f32x4*)(mo + (size_t)arow * MDIM + k0 + 4);
      a = cvt8(f1, f2);
    } else if (k0 < 144) {
      f32x4 f1 = *(const f32x4*)(ef + (size_t)arow * EFDIM + (k0 - 128));
      f32x4 f2 = *(const f32x4*)(ef + (size_t)arow * EFDIM + (k0 - 128) + 4);
      a = cvt8(f1, f2);
    } else {
      a = (s16x8){0, 0, 0, 0, 0, 0, 0, 0};
    }
#pragma unroll
    for (int f = 0; f < 8; ++f) {
      const int col = f * 16 + r;
      s16x8 b = *(const s16x8*)&w1l[col * 192 + (((step * 4 + kg) ^ (col & 7)) * 8)];
      acc[f] = mfma16(a, b, acc[f]);
    }
  }
#pragma unroll
  for (int f = 0; f < 8; ++f) {
    const int col = f * 16 + r;
    const float bias = b1[col];
#pragma unroll
    for (int j = 0; j < 4; ++j) {
      const int orow = row0 + kg * 4 + j;
      float v = acc[f][j] + bias;
      v = v > 0.f ? v : 0.f;
      msg1b[(size_t)orow * MDIM + col] = f2bf(v);
    }
  }
}

// ---------------- CSR build: histogram -> scan -> scatter ----------------
__global__ __launch_bounds__(256) void hist_kernel(const int* __restrict__ rows,
                                                   int* __restrict__ cnt, int nnz) {
  int i = blockIdx.x * 256 + threadIdx.x;
  if (i < nnz) atomicAdd(&cnt[rows[i]], 1);
}

__global__ __launch_bounds__(256) void scan1_kernel(const int* __restrict__ cnt,
                                                    int* __restrict__ excl,
                                                    int* __restrict__ bsums, int n) {
  __shared__ int wsum[4];
  const int t = threadIdx.x;
  const int base = blockIdx.x * SCAN_BLK + t * 4;
  int v[4];
#pragma unroll
  for (int j = 0; j < 4; ++j) v[j] = (base + j < n) ? cnt[base + j] : 0;
  const int s = v[0] + v[1] + v[2] + v[3];
  const int lane = t & 63, wave = t >> 6;
  int inc = s;
#pragma unroll
  for (int d = 1; d < 64; d <<= 1) {
    int o = __shfl_up(inc, d, 64);
    if (lane >= d) inc += o;
  }
  if (lane == 63) wsum[wave] = inc;
  __syncthreads();
  int woff = 0;
#pragma unroll
  for (int wv = 0; wv < 4; ++wv) if (wv < wave) woff += wsum[wv];
  int run = woff + inc - s;
#pragma unroll
  for (int j = 0; j < 4; ++j) {
    if (base + j < n) excl[base + j] = run;
    run += v[j];
  }
  if (t == 0) bsums[blockIdx.x] = wsum[0] + wsum[1] + wsum[2] + wsum[3];
}

__global__ __launch_bounds__(256) void scan2_kernel(int* __restrict__ bsums, int nb) {
  __shared__ int ws[4];
  const int t = threadIdx.x;
  const int v = (t < nb) ? bsums[t] : 0;
  const int lane = t & 63, wave = t >> 6;
  int inc = v;
#pragma unroll
  for (int d = 1; d < 64; d <<= 1) {
    int o = __shfl_up(inc, d, 64);
    if (lane >= d) inc += o;
  }
  if (lane == 63) ws[wave] = inc;
  __syncthreads();
  int woff = 0;
#pragma unroll
  for (int wv = 0; wv < 4; ++wv) if (wv < wave) woff += ws[wv];
  if (t < nb) bsums[t] = woff + inc - v;
}

__global__ __launch_bounds__(256) void scan3_kernel(int* __restrict__ row_ptr,
                                                    int* __restrict__ row_fill,
                                                    const int* __restrict__ bsums, int n) {
  int i = blockIdx.x * 256 + threadIdx.x;
  if (i >= n) return;
  int v = row_ptr[i] + bsums[i / SCAN_BLK];
  row_ptr[i] = v;
  row_fill[i] = v;
}

__global__ __launch_bounds__(256) void scatter_kernel(
    const int* __restrict__ rows, const int* __restrict__ cols,
    const float* __restrict__ vals, int* __restrict__ row_fill,
    int2* __restrict__ csr, int nnz) {
  int i = blockIdx.x * 256 + threadIdx.x;
  if (i >= nnz) return;
  int r = rows[i];
  int idx = atomicAdd(&row_fill[r], 1);
  int2 cv;
  cv.x = cols[i];
  cv.y = __float_as_int(vals[i]);
  csr[idx] = cv;
}

// ---------------- gather SpMM: one wave per row, 2-stage pipeline ----------------
__global__ __launch_bounds__(256) void gather_kernel(
    const int* __restrict__ row_ptr, const int2* __restrict__ csr,
    const ushort* __restrict__ msg1b, ushort* __restrict__ msg2b,
    int E, int nnz) {
  const int w = (blockIdx.x * 256 + threadIdx.x) >> 6;
  if (w >= E) return;
  const int lane = threadIdx.x & 63;
  const int start = row_ptr[w];
  const int end = (w == E - 1) ? nnz : row_ptr[w + 1];
  float a0 = 0.f, a1 = 0.f;

  int2 cvA = {0, 0}, cvB = {0, 0};
  ushort2 mA = {0, 0};
  if (start < end) {
    cvA = csr[start];
    mA = *(const ushort2*)(msg1b + (size_t)cvA.x * MDIM + lane * 2);
  }
  if (start + 1 < end) cvB = csr[start + 1];

  for (int j = start; j < end; ++j) {
    int2 cvC = cvB;
    ushort2 mB = mA;
    if (j + 2 < end) cvC = csr[j + 2];
    if (j + 1 < end) mB = *(const ushort2*)(msg1b + (size_t)cvB.x * MDIM + lane * 2);
    const float val = __int_as_float(cvA.y);
    a0 += bf2f(mA.x) * val;
    a1 += bf2f(mA.y) * val;
    cvA = cvB; cvB = cvC; mA = mB;
  }
  ushort2 o;
  o.x = f2bf(a0);
  o.y = f2bf(a1);
  *(ushort2*)(msg2b + (size_t)w * MDIM + lane * 2) = o;
}

// ---------------- msg3 = relu(msg2 @ W2^T + b2), bf16 out ----------------
// linear1 pattern: W2 (32KB) staged once, swizzled; A direct from global bf16.
__global__ __launch_bounds__(256) void msg3_kernel(
    const ushort* __restrict__ msg2b, const ushort* __restrict__ W2b,
    const float* __restrict__ b2, ushort* __restrict__ msg3b) {
  __shared__ ushort w2l[128 * 128];  // 32KB
  const int tid = threadIdx.x;
  const int wave = tid >> 6, lane = tid & 63;
  const int r = lane & 15, kg = lane >> 4;
  const int row0 = blockIdx.x * 64 + wave * 16;

#pragma unroll
  for (int l = 0; l < 8; ++l) {
    const int gid = l * 256 + tid;
    const int row = gid >> 4, g = gid & 15;
    uint4 v = *(const uint4*)(W2b + row * MDIM + g * 8);
    *(uint4*)&w2l[row * 128 + ((g * 8) ^ ((row & 7) << 3))] = v;
  }

  s16x8 a1[4];
#pragma unroll
  for (int step = 0; step < 4; ++step)
    a1[step] = *(const s16x8*)(msg2b + (size_t)(row0 + r) * MDIM + step * 32 + kg * 8);
  __syncthreads();

  f32x4 acc[8] = {};
#pragma unroll
  for (int step = 0; step < 4; ++step) {
    const int k0 = step * 32 + kg * 8;
#pragma unroll
    for (int f = 0; f < 8; ++f) {
      const int col = f * 16 + r;
      s16x8 b = *(const s16x8*)&w2l[col * 128 + (k0 ^ ((col & 7) << 3))];
      acc[f] = mfma16(a1[step], b, acc[f]);
    }
  }
#pragma unroll
  for (int f = 0; f < 8; ++f) {
    const int col = f * 16 + r;
    const float bias = b2[col];
#pragma unroll
    for (int j = 0; j < 4; ++j) {
      const int orow = row0 + kg * 4 + j;
      float v = acc[f][j] + bias;
      v = v > 0.f ? v : 0.f;
      msg3b[(size_t)orow * MDIM + col] = f2bf(v);
    }
  }
}

// ---------------- gate_kernel: GRU gates, 4-way column split ----------------
// grid = 4 cgroups x ceil(E/128). Block: 512 thr / 8 waves, 128 rows, 32 cols.
// Stages 48KB of gate weights ONCE (1 barrier), then barrier-free:
// per wave 2 phases x (24 ds_read_b128 + 24 MFMA) + epilogue in registers.
// Column split aligns output rows to distinct 128B lines -> no write amplification.
__global__ __launch_bounds__(512, 4) void gate_kernel(
    const ushort* __restrict__ msg3b, const float* __restrict__ mo,
    const ushort* __restrict__ Wihb, const ushort* __restrict__ Whhb,
    const float* __restrict__ bih, const float* __restrict__ bhh,
    float* __restrict__ out, int E) {
  __shared__ ushort wl[6 * 4096];  // 48KB: sec l = [l*4096, +4096), 32 rows x 128
  const int tid = threadIdx.x;
  const int cg = blockIdx.x & 3;
  const int row0 = (blockIdx.x >> 2) * 128;
  const int wave = tid >> 6, lane = tid & 63;
  const int r = lane & 15, kg = lane >> 4;

  // stage weights: sec l, local row lr (0..31), granule g (0..15)
  const int lr = tid >> 4, g = tid & 15;
#pragma unroll
  for (int l = 0; l < 6; ++l) {
    const ushort* src = (l & 1) ? Whhb : Wihb;
    const int gate = l >> 1;
    uint4 v = *(const uint4*)(src + (size_t)(gate * 128 + cg * 32 + lr) * MDIM + g * 8);
    *(uint4*)&wl[l * 4096 + lr * 128 + ((g * 8) ^ ((lr & 7) << 3))] = v;
  }

  // A-fragments (row-clamped)
  const int arow0 = row0 + wave * 16 + r;
  const int arow = arow0 < E ? arow0 : E - 1;
  s16x8 ai[4], ah[4];
#pragma unroll
  for (int step = 0; step < 4; ++step) {
    const int k0 = step * 32 + kg * 8;
    ai[step] = *(const s16x8*)(msg3b + (size_t)arow * MDIM + k0);
    f32x4 f1 = *(const f32x4*)(mo + (size_t)arow * MDIM + k0);
    f32x4 f2 = *(const f32x4*)(mo + (size_t)arow * MDIM + k0 + 4);
    ah[step] = cvt8(f1, f2);
  }
  __syncthreads();

  float outv[8];
#pragma unroll
  for (int p = 0; p < 2; ++p) {
    const int slr = p * 16 + r;           // section-local weight row
    f32x4 a_ir = {}, a_hr = {}, a_iz = {}, a_hz = {}, a_in = {}, a_hn = {};
#pragma unroll
    for (int step = 0; step < 4; ++step) {
      const int k0 = step * 32 + kg * 8;
      const int sw = slr * 128 + (k0 ^ ((slr & 7) << 3));
      s16x8 b_ir = *(const s16x8*)&wl[0 * 4096 + sw];
      s16x8 b_hr = *(const s16x8*)&wl[1 * 4096 + sw];
      a_ir = mfma16(ai[step], b_ir, a_ir);
      a_hr = mfma16(ah[step], b_hr, a_hr);
      s16x8 b_iz = *(const s16x8*)&wl[2 * 4096 + sw];
      s16x8 b_hz = *(const s16x8*)&wl[3 * 4096 + sw];
      a_iz = mfma16(ai[step], b_iz, a_iz);
      a_hz = mfma16(ah[step], b_hz, a_hz);
      s16x8 b_in = *(const s16x8*)&wl[4 * 4096 + sw];
      s16x8 b_hn = *(const s16x8*)&wl[5 * 4096 + sw];
      a_in = mfma16(ai[step], b_in, a_in);
      a_hn = mfma16(ah[step], b_hn, a_hn);
    }
    const int c128 = cg * 32 + p * 16 + r;
    const float bi_r = bih[c128], bh_r = bhh[c128];
    const float bi_z = bih[128 + c128], bh_z = bhh[128 + c128];
    const float bi_n = bih[256 + c128], bh_n = bhh[256 + c128];
#pragma unroll
    for (int j = 0; j < 4; ++j) {
      const int orow0 = row0 + wave * 16 + kg * 4 + j;
      const int orow = orow0 < E ? orow0 : E - 1;
      const float rr_ = sigmoidf_((a_ir[j] + bi_r) + (a_hr[j] + bh_r));
      const float zz = sigmoidf_((a_iz[j] + bi_z) + (a_hz[j] + bh_z));
      const float nn = tanhf_((a_in[j] + bi_n) + rr_ * (a_hn[j] + bh_n));
      const float m = mo[(size_t)orow * MDIM + c128];
      outv[p * 4 + j] = (1.f - zz) * nn + zz * m;
    }
  }

  // store burst: per quarter-wave 64B segments; p=0/1 halves complete a 128B line
#pragma unroll
  for (int p = 0; p < 2; ++p) {
    const int c128 = cg * 32 + p * 16 + r;
#pragma unroll
    for (int j = 0; j < 4; ++j) {
      const int orow = row0 + wave * 16 + kg * 4 + j;
      if (orow < E) out[(size_t)orow * MDIM + c128] = outv[p * 4 + j];
    }
  }
}

extern "C" void kernel_launch(void* const* d_in, const int* in_sizes, int n_in,
                              void* d_out, int out_size, void* d_ws, size_t ws_size,
                              hipStream_t stream) {
  const float* ef   = (const float*)d_in[0];
  const float* mo   = (const float*)d_in[1];
  const int*   arow = (const int*)d_in[2];
  const int*   acol = (const int*)d_in[3];
  const float* aval = (const float*)d_in[4];
  const float* W1   = (const float*)d_in[5];
  const float* b1   = (const float*)d_in[6];
  const float* W2   = (const float*)d_in[7];
  const float* b2   = (const float*)d_in[8];
  const float* Wih  = (const float*)d_in[9];
  const float* Whh  = (const float*)d_in[10];
  const float* bih  = (const float*)d_in[11];
  const float* bhh  = (const float*)d_in[12];
  float* out = (float*)d_out;

  const int E   = in_sizes[0] / EFDIM;   // 200000
  const int nnz = in_sizes[2];           // 1600000

  char* w = (char*)d_ws;
  size_t off = 0;
  ushort* msg1b   = (ushort*)(w + off); off += (size_t)E * MDIM * 2;   // 51.2 MB
  ushort* msg2b   = (ushort*)(w + off); off += (size_t)E * MDIM * 2;   // 51.2 MB
  ushort* msg3b   = (ushort*)(w + off); off += (size_t)E * MDIM * 2;   // 51.2 MB
  int*    row_cnt = (int*)(w + off);    off += (size_t)E * 4;
  int*    row_ptr = (int*)(w + off);    off += (size_t)E * 4;
  int*    row_fill= (int*)(w + off);    off += (size_t)E * 4;
  int*    bsums   = (int*)(w + off);    off += 256 * 4;
  int2*   csr     = (int2*)(w + off);   off += (size_t)nnz * 8;        // 12.8 MB
  ushort* W1b     = (ushort*)(w + off); off += 128 * K1PAD * 2;
  ushort* W2b     = (ushort*)(w + off); off += 128 * 128 * 2;
  ushort* Wihb    = (ushort*)(w + off); off += 384 * 128 * 2;
  ushort* Whhb    = (ushort*)(w + off); off += 384 * 128 * 2;
  if (off > ws_size) return;  // needs ~170 MB

  const int prep_elems = 128 * K1PAD + 128 * 128 + 2 * 384 * 128;
  prep_kernel<<<(prep_elems + 255) / 256, 256, 0, stream>>>(W1, W2, Wih, Whh,
                                                            W1b, W2b, Wihb, Whhb);
  // linear1
  linear1_kernel<<<E / 64, 256, 0, stream>>>(mo, ef, W1b, b1, msg1b);

  // CSR build
  hipMemsetAsync(row_cnt, 0, (size_t)E * 4, stream);
  hist_kernel<<<(nnz + 255) / 256, 256, 0, stream>>>(arow, row_cnt, nnz);
  const int nscan = (E + SCAN_BLK - 1) / SCAN_BLK;  // 196 blocks
  scan1_kernel<<<nscan, 256, 0, stream>>>(row_cnt, row_ptr, bsums, E);
  scan2_kernel<<<1, 256, 0, stream>>>(bsums, nscan);
  scan3_kernel<<<(E + 255) / 256, 256, 0, stream>>>(row_ptr, row_fill, bsums, E);
  scatter_kernel<<<(nnz + 255) / 256, 256, 0, stream>>>(arow, acol, aval, row_fill, csr, nnz);

  // gather SpMM
  {
    const long long total = (long long)E * 64;
    const int grid = (int)((total + 255) / 256);
    gather_kernel<<<grid, 256, 0, stream>>>(row_ptr, csr, msg1b, msg2b, E, nnz);
  }

  // linear2 + GRU gates
  msg3_kernel<<<E / 64, 256, 0, stream>>>(msg2b, W2b, b2, msg3b);
  {
    const int nrt = (E + 127) / 128;
    gate_kernel<<<nrt * 4, 512, 0, stream>>>(msg3b, mo, Wihb, Whhb, bih, bhh, out, E);
  }
}

// Round 7
// 450.209 us; speedup vs baseline: 1.4209x; 1.1162x over previous
//
#include <hip/hip_runtime.h>
#include <hip/hip_bf16.h>

// EdgeGNN layer: linear1(relu) -> SpMM (CSR counting-sort + gather) -> linear2(relu) -> GRUCell
// E=200000, NNZ=1600000, EF=16, M=128. bf16 MFMA for GEMMs; no f32 atomics.
// R6: (a) gate_kernel gets a bijective XCD-aware blockIdx swizzle so the 4
//     column-group blocks sharing the same A-rows land on the SAME XCD's L2
//     (R5 counters: FETCH 306MB vs ~154MB ideal = cross-XCD A re-fetch);
//     out stores made nontemporal. (b) gather_kernel rebuilt: 16 lanes x 16B
//     per nnz, 4 nnz streams per wave, shfl_xor reduction (4x fewer, 4x wider
//     gather loads).

typedef __attribute__((ext_vector_type(4))) float f32x4;
typedef __attribute__((ext_vector_type(8))) short s16x8;

#define MDIM 128
#define EFDIM 16
#define K1PAD 160   // 144 padded to 5*32
#define SCAN_BLK 1024

__device__ __forceinline__ ushort f2bf(float f) {
  union { float f; unsigned u; } v; v.f = f;
  unsigned u = v.u;
  unsigned r = (u + 0x7fffu + ((u >> 16) & 1u)) >> 16;  // RNE
  return (ushort)r;
}
__device__ __forceinline__ float bf2f(ushort h) {
  union { unsigned u; float f; } v; v.u = ((unsigned)h) << 16; return v.f;
}
__device__ __forceinline__ s16x8 cvt8(f32x4 a, f32x4 b) {
  s16x8 o;
  o[0] = (short)f2bf(a[0]); o[1] = (short)f2bf(a[1]);
  o[2] = (short)f2bf(a[2]); o[3] = (short)f2bf(a[3]);
  o[4] = (short)f2bf(b[0]); o[5] = (short)f2bf(b[1]);
  o[6] = (short)f2bf(b[2]); o[7] = (short)f2bf(b[3]);
  return o;
}
__device__ __forceinline__ f32x4 mfma16(s16x8 a, s16x8 b, f32x4 c) {
  return __builtin_amdgcn_mfma_f32_16x16x32_bf16(a, b, c, 0, 0, 0);
}
__device__ __forceinline__ float sigmoidf_(float x) { return 1.f / (1.f + __expf(-x)); }
__device__ __forceinline__ float tanhf_(float x) {
  float xc = fminf(fmaxf(x, -15.f), 15.f);
  float t = __expf(2.f * xc);
  return (t - 1.f) / (t + 1.f);
}

// ---------------- prep: bf16 weight conversion ----------------
__global__ __launch_bounds__(256) void prep_kernel(
    const float* __restrict__ W1, const float* __restrict__ W2,
    const float* __restrict__ Wih, const float* __restrict__ Whh,
    ushort* __restrict__ W1b, ushort* __restrict__ W2b,
    ushort* __restrict__ Wihb, ushort* __restrict__ Whhb) {
  int idx = blockIdx.x * 256 + threadIdx.x;
  if (idx < 128 * K1PAD) {
    int n = idx / K1PAD, k = idx % K1PAD;
    W1b[idx] = (k < 144) ? f2bf(W1[n * 144 + k]) : (ushort)0;
    return;
  }
  int i2 = idx - 128 * K1PAD;
  if (i2 < 128 * 128) { W2b[i2] = f2bf(W2[i2]); return; }
  int i3 = i2 - 128 * 128;
  if (i3 < 384 * 128) { Wihb[i3] = f2bf(Wih[i3]); return; }
  int i4 = i3 - 384 * 128;
  if (i4 < 384 * 128) { Whhb[i4] = f2bf(Whh[i4]); return; }
}

// ---------------- K1: msg1 = relu(concat(mo,ef) @ W1^T + b1), bf16 out ----------------
__global__ __launch_bounds__(256) void linear1_kernel(
    const float* __restrict__ mo, const float* __restrict__ ef,
    const ushort* __restrict__ W1b, const float* __restrict__ b1,
    ushort* __restrict__ msg1b) {
  __shared__ ushort w1l[128 * 192];  // 48KB
  const int tid = threadIdx.x;
  const int wave = tid >> 6, lane = tid & 63;
  const int r = lane & 15, kg = lane >> 4;
  const int row0 = blockIdx.x * 64 + wave * 16;
  const int arow = row0 + r;

#pragma unroll
  for (int l = 0; l < 10; ++l) {
    const int gid = l * 256 + tid;
    const int row = gid / 20, g = gid - row * 20;
    uint4 v = *(const uint4*)(W1b + row * K1PAD + g * 8);
    *(uint4*)&w1l[row * 192 + ((g ^ (row & 7)) * 8)] = v;
  }
  __syncthreads();

  f32x4 acc[8] = {};
#pragma unroll
  for (int step = 0; step < 5; ++step) {
    const int k0 = step * 32 + kg * 8;
    s16x8 a;
    if (k0 < 128) {
      f32x4 f1 = *(const f32x4*)(mo + (size_t)arow * MDIM + k0);
      f32x4 f2 = *(const f32x4*)(mo + (size_t)arow * MDIM + k0 + 4);
      a = cvt8(f1, f2);
    } else if (k0 < 144) {
      f32x4 f1 = *(const f32x4*)(ef + (size_t)arow * EFDIM + (k0 - 128));
      f32x4 f2 = *(const f32x4*)(ef + (size_t)arow * EFDIM + (k0 - 128) + 4);
      a = cvt8(f1, f2);
    } else {
      a = (s16x8){0, 0, 0, 0, 0, 0, 0, 0};
    }
#pragma unroll
    for (int f = 0; f < 8; ++f) {
      const int col = f * 16 + r;
      s16x8 b = *(const s16x8*)&w1l[col * 192 + (((step * 4 + kg) ^ (col & 7)) * 8)];
      acc[f] = mfma16(a, b, acc[f]);
    }
  }
#pragma unroll
  for (int f = 0; f < 8; ++f) {
    const int col = f * 16 + r;
    const float bias = b1[col];
#pragma unroll
    for (int j = 0; j < 4; ++j) {
      const int orow = row0 + kg * 4 + j;
      float v = acc[f][j] + bias;
      v = v > 0.f ? v : 0.f;
      msg1b[(size_t)orow * MDIM + col] = f2bf(v);
    }
  }
}

// ---------------- CSR build: histogram -> scan -> scatter ----------------
__global__ __launch_bounds__(256) void hist_kernel(const int* __restrict__ rows,
                                                   int* __restrict__ cnt, int nnz) {
  int i = blockIdx.x * 256 + threadIdx.x;
  if (i < nnz) atomicAdd(&cnt[rows[i]], 1);
}

__global__ __launch_bounds__(256) void scan1_kernel(const int* __restrict__ cnt,
                                                    int* __restrict__ excl,
                                                    int* __restrict__ bsums, int n) {
  __shared__ int wsum[4];
  const int t = threadIdx.x;
  const int base = blockIdx.x * SCAN_BLK + t * 4;
  int v[4];
#pragma unroll
  for (int j = 0; j < 4; ++j) v[j] = (base + j < n) ? cnt[base + j] : 0;
  const int s = v[0] + v[1] + v[2] + v[3];
  const int lane = t & 63, wave = t >> 6;
  int inc = s;
#pragma unroll
  for (int d = 1; d < 64; d <<= 1) {
    int o = __shfl_up(inc, d, 64);
    if (lane >= d) inc += o;
  }
  if (lane == 63) wsum[wave] = inc;
  __syncthreads();
  int woff = 0;
#pragma unroll
  for (int wv = 0; wv < 4; ++wv) if (wv < wave) woff += wsum[wv];
  int run = woff + inc - s;
#pragma unroll
  for (int j = 0; j < 4; ++j) {
    if (base + j < n) excl[base + j] = run;
    run += v[j];
  }
  if (t == 0) bsums[blockIdx.x] = wsum[0] + wsum[1] + wsum[2] + wsum[3];
}

__global__ __launch_bounds__(256) void scan2_kernel(int* __restrict__ bsums, int nb) {
  __shared__ int ws[4];
  const int t = threadIdx.x;
  const int v = (t < nb) ? bsums[t] : 0;
  const int lane = t & 63, wave = t >> 6;
  int inc = v;
#pragma unroll
  for (int d = 1; d < 64; d <<= 1) {
    int o = __shfl_up(inc, d, 64);
    if (lane >= d) inc += o;
  }
  if (lane == 63) ws[wave] = inc;
  __syncthreads();
  int woff = 0;
#pragma unroll
  for (int wv = 0; wv < 4; ++wv) if (wv < wave) woff += ws[wv];
  if (t < nb) bsums[t] = woff + inc - v;
}

__global__ __launch_bounds__(256) void scan3_kernel(int* __restrict__ row_ptr,
                                                    int* __restrict__ row_fill,
                                                    const int* __restrict__ bsums, int n) {
  int i = blockIdx.x * 256 + threadIdx.x;
  if (i >= n) return;
  int v = row_ptr[i] + bsums[i / SCAN_BLK];
  row_ptr[i] = v;
  row_fill[i] = v;
}

__global__ __launch_bounds__(256) void scatter_kernel(
    const int* __restrict__ rows, const int* __restrict__ cols,
    const float* __restrict__ vals, int* __restrict__ row_fill,
    int2* __restrict__ csr, int nnz) {
  int i = blockIdx.x * 256 + threadIdx.x;
  if (i >= nnz) return;
  int r = rows[i];
  int idx = atomicAdd(&row_fill[r], 1);
  int2 cv;
  cv.x = cols[i];
  cv.y = __float_as_int(vals[i]);
  csr[idx] = cv;
}

// ---------------- gather SpMM: one wave per row, 4 nnz streams x 16 lanes ----------------
// lane = sub*16 + c: sub picks the nnz substream (j = start+sub, step 4),
// c picks 8 columns (16B ushort8 load). Final: shfl_xor(16,32) reduce, sub==0 writes.
__global__ __launch_bounds__(256) void gather_kernel(
    const int* __restrict__ row_ptr, const int2* __restrict__ csr,
    const ushort* __restrict__ msg1b, ushort* __restrict__ msg2b,
    int E, int nnz) {
  const int w = (blockIdx.x * 256 + threadIdx.x) >> 6;
  if (w >= E) return;
  const int lane = threadIdx.x & 63;
  const int sub = lane >> 4, c = lane & 15;
  const int start = row_ptr[w];
  const int end = (w == E - 1) ? nnz : row_ptr[w + 1];

  float acc[8] = {};
  int j = start + sub;
  if (j < end) {
    int2 cv = csr[j];
    while (true) {
      const int jn = j + 4;
      const bool more = jn < end;
      int2 cvn = cv;
      if (more) cvn = csr[jn];
      const float val = __int_as_float(cv.y);
      const s16x8 m = *(const s16x8*)(msg1b + (size_t)cv.x * MDIM + c * 8);
#pragma unroll
      for (int t = 0; t < 8; ++t) acc[t] += bf2f((ushort)m[t]) * val;
      if (!more) break;
      cv = cvn;
      j = jn;
    }
  }
#pragma unroll
  for (int t = 0; t < 8; ++t) {
    acc[t] += __shfl_xor(acc[t], 16, 64);
    acc[t] += __shfl_xor(acc[t], 32, 64);
  }
  if (sub == 0) {
    s16x8 o;
#pragma unroll
    for (int t = 0; t < 8; ++t) o[t] = (short)f2bf(acc[t]);
    *(s16x8*)(msg2b + (size_t)w * MDIM + c * 8) = o;
  }
}

// ---------------- msg3 = relu(msg2 @ W2^T + b2), bf16 out ----------------
__global__ __launch_bounds__(256) void msg3_kernel(
    const ushort* __restrict__ msg2b, const ushort* __restrict__ W2b,
    const float* __restrict__ b2, ushort* __restrict__ msg3b) {
  __shared__ ushort w2l[128 * 128];  // 32KB
  const int tid = threadIdx.x;
  const int wave = tid >> 6, lane = tid & 63;
  const int r = lane & 15, kg = lane >> 4;
  const int row0 = blockIdx.x * 64 + wave * 16;

#pragma unroll
  for (int l = 0; l < 8; ++l) {
    const int gid = l * 256 + tid;
    const int row = gid >> 4, g = gid & 15;
    uint4 v = *(const uint4*)(W2b + row * MDIM + g * 8);
    *(uint4*)&w2l[row * 128 + ((g * 8) ^ ((row & 7) << 3))] = v;
  }

  s16x8 a1[4];
#pragma unroll
  for (int step = 0; step < 4; ++step)
    a1[step] = *(const s16x8*)(msg2b + (size_t)(row0 + r) * MDIM + step * 32 + kg * 8);
  __syncthreads();

  f32x4 acc[8] = {};
#pragma unroll
  for (int step = 0; step < 4; ++step) {
    const int k0 = step * 32 + kg * 8;
#pragma unroll
    for (int f = 0; f < 8; ++f) {
      const int col = f * 16 + r;
      s16x8 b = *(const s16x8*)&w2l[col * 128 + (k0 ^ ((col & 7) << 3))];
      acc[f] = mfma16(a1[step], b, acc[f]);
    }
  }
#pragma unroll
  for (int f = 0; f < 8; ++f) {
    const int col = f * 16 + r;
    const float bias = b2[col];
#pragma unroll
    for (int j = 0; j < 4; ++j) {
      const int orow = row0 + kg * 4 + j;
      float v = acc[f][j] + bias;
      v = v > 0.f ? v : 0.f;
      msg3b[(size_t)orow * MDIM + col] = f2bf(v);
    }
  }
}

// ---------------- gate_kernel: GRU gates, 4-way column split ----------------
// XCD-aware bijective swizzle (m204): the 4 cg-blocks of a row-tile get
// contiguous wgids -> same XCD -> A-panels (msg3, mo) hit that XCD's L2.
__global__ __launch_bounds__(512, 4) void gate_kernel(
    const ushort* __restrict__ msg3b, const float* __restrict__ mo,
    const ushort* __restrict__ Wihb, const ushort* __restrict__ Whhb,
    const float* __restrict__ bih, const float* __restrict__ bhh,
    float* __restrict__ out, int E) {
  __shared__ ushort wl[6 * 4096];  // 48KB: sec l = [l*4096, +4096), 32 rows x 128
  const int tid = threadIdx.x;

  const int nwg = gridDim.x;
  const int orig = blockIdx.x;
  const int q = nwg >> 3, rm = nwg & 7;
  const int xcd = orig & 7, idx = orig >> 3;
  const int wgid = (xcd < rm ? xcd * (q + 1) : rm * (q + 1) + (xcd - rm) * q) + idx;
  const int cg = wgid & 3;
  const int row0 = (wgid >> 2) * 128;

  const int wave = tid >> 6, lane = tid & 63;
  const int r = lane & 15, kg = lane >> 4;

  // stage weights: sec l, local row lr (0..31), granule g (0..15)
  const int lr = tid >> 4, g = tid & 15;
#pragma unroll
  for (int l = 0; l < 6; ++l) {
    const ushort* src = (l & 1) ? Whhb : Wihb;
    const int gate = l >> 1;
    uint4 v = *(const uint4*)(src + (size_t)(gate * 128 + cg * 32 + lr) * MDIM + g * 8);
    *(uint4*)&wl[l * 4096 + lr * 128 + ((g * 8) ^ ((lr & 7) << 3))] = v;
  }

  // A-fragments (row-clamped)
  const int arow0 = row0 + wave * 16 + r;
  const int arow = arow0 < E ? arow0 : E - 1;
  s16x8 ai[4], ah[4];
#pragma unroll
  for (int step = 0; step < 4; ++step) {
    const int k0 = step * 32 + kg * 8;
    ai[step] = *(const s16x8*)(msg3b + (size_t)arow * MDIM + k0);
    f32x4 f1 = *(const f32x4*)(mo + (size_t)arow * MDIM + k0);
    f32x4 f2 = *(const f32x4*)(mo + (size_t)arow * MDIM + k0 + 4);
    ah[step] = cvt8(f1, f2);
  }
  __syncthreads();

  float outv[8];
#pragma unroll
  for (int p = 0; p < 2; ++p) {
    const int slr = p * 16 + r;           // section-local weight row
    f32x4 a_ir = {}, a_hr = {}, a_iz = {}, a_hz = {}, a_in = {}, a_hn = {};
#pragma unroll
    for (int step = 0; step < 4; ++step) {
      const int k0 = step * 32 + kg * 8;
      const int sw = slr * 128 + (k0 ^ ((slr & 7) << 3));
      s16x8 b_ir = *(const s16x8*)&wl[0 * 4096 + sw];
      s16x8 b_hr = *(const s16x8*)&wl[1 * 4096 + sw];
      a_ir = mfma16(ai[step], b_ir, a_ir);
      a_hr = mfma16(ah[step], b_hr, a_hr);
      s16x8 b_iz = *(const s16x8*)&wl[2 * 4096 + sw];
      s16x8 b_hz = *(const s16x8*)&wl[3 * 4096 + sw];
      a_iz = mfma16(ai[step], b_iz, a_iz);
      a_hz = mfma16(ah[step], b_hz, a_hz);
      s16x8 b_in = *(const s16x8*)&wl[4 * 4096 + sw];
      s16x8 b_hn = *(const s16x8*)&wl[5 * 4096 + sw];
      a_in = mfma16(ai[step], b_in, a_in);
      a_hn = mfma16(ah[step], b_hn, a_hn);
    }
    const int c128 = cg * 32 + p * 16 + r;
    const float bi_r = bih[c128], bh_r = bhh[c128];
    const float bi_z = bih[128 + c128], bh_z = bhh[128 + c128];
    const float bi_n = bih[256 + c128], bh_n = bhh[256 + c128];
#pragma unroll
    for (int j = 0; j < 4; ++j) {
      const int orow0 = row0 + wave * 16 + kg * 4 + j;
      const int orow = orow0 < E ? orow0 : E - 1;
      const float rr_ = sigmoidf_((a_ir[j] + bi_r) + (a_hr[j] + bh_r));
      const float zz = sigmoidf_((a_iz[j] + bi_z) + (a_hz[j] + bh_z));
      const float nn = tanhf_((a_in[j] + bi_n) + rr_ * (a_hn[j] + bh_n));
      const float m = mo[(size_t)orow * MDIM + c128];
      outv[p * 4 + j] = (1.f - zz) * nn + zz * m;
    }
  }

  // store burst; nontemporal (out is never re-read; keep L2 for A panels)
#pragma unroll
  for (int p = 0; p < 2; ++p) {
    const int c128 = cg * 32 + p * 16 + r;
#pragma unroll
    for (int j = 0; j < 4; ++j) {
      const int orow = row0 + wave * 16 + kg * 4 + j;
      if (orow < E)
        __builtin_nontemporal_store(outv[p * 4 + j], out + (size_t)orow * MDIM + c128);
    }
  }
}

extern "C" void kernel_launch(void* const* d_in, const int* in_sizes, int n_in,
                              void* d_out, int out_size, void* d_ws, size_t ws_size,
                              hipStream_t stream) {
  const float* ef   = (const float*)d_in[0];
  const float* mo   = (const float*)d_in[1];
  const int*   arow = (const int*)d_in[2];
  const int*   acol = (const int*)d_in[3];
  const float* aval = (const float*)d_in[4];
  const float* W1   = (const float*)d_in[5];
  const float* b1   = (const float*)d_in[6];
  const float* W2   = (const float*)d_in[7];
  const float* b2   = (const float*)d_in[8];
  const float* Wih  = (const float*)d_in[9];
  const float* Whh  = (const float*)d_in[10];
  const float* bih  = (const float*)d_in[11];
  const float* bhh  = (const float*)d_in[12];
  float* out = (float*)d_out;

  const int E   = in_sizes[0] / EFDIM;   // 200000
  const int nnz = in_sizes[2];           // 1600000

  char* w = (char*)d_ws;
  size_t off = 0;
  ushort* msg1b   = (ushort*)(w + off); off += (size_t)E * MDIM * 2;   // 51.2 MB
  ushort* msg2b   = (ushort*)(w + off); off += (size_t)E * MDIM * 2;   // 51.2 MB
  ushort* msg3b   = (ushort*)(w + off); off += (size_t)E * MDIM * 2;   // 51.2 MB
  int*    row_cnt = (int*)(w + off);    off += (size_t)E * 4;
  int*    row_ptr = (int*)(w + off);    off += (size_t)E * 4;
  int*    row_fill= (int*)(w + off);    off += (size_t)E * 4;
  int*    bsums   = (int*)(w + off);    off += 256 * 4;
  int2*   csr     = (int2*)(w + off);   off += (size_t)nnz * 8;        // 12.8 MB
  ushort* W1b     = (ushort*)(w + off); off += 128 * K1PAD * 2;
  ushort* W2b     = (ushort*)(w + off); off += 128 * 128 * 2;
  ushort* Wihb    = (ushort*)(w + off); off += 384 * 128 * 2;
  ushort* Whhb    = (ushort*)(w + off); off += 384 * 128 * 2;
  if (off > ws_size) return;  // needs ~170 MB

  const int prep_elems = 128 * K1PAD + 128 * 128 + 2 * 384 * 128;
  prep_kernel<<<(prep_elems + 255) / 256, 256, 0, stream>>>(W1, W2, Wih, Whh,
                                                            W1b, W2b, Wihb, Whhb);
  // linear1
  linear1_kernel<<<E / 64, 256, 0, stream>>>(mo, ef, W1b, b1, msg1b);

  // CSR build
  hipMemsetAsync(row_cnt, 0, (size_t)E * 4, stream);
  hist_kernel<<<(nnz + 255) / 256, 256, 0, stream>>>(arow, row_cnt, nnz);
  const int nscan = (E + SCAN_BLK - 1) / SCAN_BLK;  // 196 blocks
  scan1_kernel<<<nscan, 256, 0, stream>>>(row_cnt, row_ptr, bsums, E);
  scan2_kernel<<<1, 256, 0, stream>>>(bsums, nscan);
  scan3_kernel<<<(E + 255) / 256, 256, 0, stream>>>(row_ptr, row_fill, bsums, E);
  scatter_kernel<<<(nnz + 255) / 256, 256, 0, stream>>>(arow, acol, aval, row_fill, csr, nnz);

  // gather SpMM
  {
    const long long total = (long long)E * 64;
    const int grid = (int)((total + 255) / 256);
    gather_kernel<<<grid, 256, 0, stream>>>(row_ptr, csr, msg1b, msg2b, E, nnz);
  }

  // linear2 + GRU gates
  msg3_kernel<<<E / 64, 256, 0, stream>>>(msg2b, W2b, b2, msg3b);
  {
    const int nrt = (E + 127) / 128;
    gate_kernel<<<nrt * 4, 512, 0, stream>>>(msg3b, mo, Wihb, Whhb, bih, bhh, out, E);
  }
}